// Round 8
// baseline (622.143 us; speedup 1.0000x reference)
//
#include <hip/hip_runtime.h>
#include <math.h>

#define NN 1024
#define BB 2
#define GG 64
#define LL 16
#define ND 256
#define H1 1024
#define ED 16

// ---------- fast device math ----------
__device__ __forceinline__ float fsig(float x) {
  return __builtin_amdgcn_rcpf(1.0f + __builtin_amdgcn_exp2f(-1.44269504f * x));
}

__device__ __forceinline__ float erf_as(float x) {
  // Abramowitz-Stegun 7.1.26, branchless, |err| < 1.5e-7
  float ax = fabsf(x);
  float t = __builtin_amdgcn_rcpf(fmaf(0.3275911f, ax, 1.0f));
  float p = fmaf(1.061405429f, t, -1.453152027f);
  p = fmaf(p, t, 1.421413741f);
  p = fmaf(p, t, -0.284496736f);
  p = fmaf(p, t, 0.254829592f);
  p *= t;
  float ex = __builtin_amdgcn_exp2f(-1.44269504f * ax * ax);
  float r = fmaf(-p, ex, 1.0f);
  return copysignf(r, x);
}

__device__ __forceinline__ float gelu_f(float x) {
  return 0.5f * x * (1.0f + erf_as(0.70710678118f * x));
}

// ---------- K1: nf (FFN + ct_emb + LN), data_ligand, one-time param prep ----------
// identity: where(same, ffn(te*s), ffn(exp_t)) == ffn(exp_t) since exp_t==te*s when same.
__global__ __launch_bounds__(256) void k_nf(
    const float* __restrict__ x, const float* __restrict__ te, const int* __restrict__ ct,
    const float* __restrict__ scal, const float* __restrict__ W1, const float* __restrict__ b1,
    const float* __restrict__ W2, const float* __restrict__ b2, const float* __restrict__ ctemb,
    const float* __restrict__ lng, const float* __restrict__ lnb, const int* __restrict__ lig,
    const float* __restrict__ wsv, const float* __restrict__ w1e, const float* __restrict__ w2e,
    const float* __restrict__ Wl1,
    float* __restrict__ dl_ws, float* __restrict__ sp_ws, float* __restrict__ w1t_ws,
    float* __restrict__ nf_out)
{
  __shared__ float s_exp[2 * 64];     // [p][g]
  __shared__ float s_h[H1 * 3];       // [c][p], stride 3 (gcd(3,32)=1 -> conflict-free writes)
  __shared__ float s_part[8 * 256];   // [w*2+p][oc]
  __shared__ float s_z[2 * 256];      // pre-LN

  const int t = threadIdx.x, bid = blockIdx.x;
  const int b = bid >> 9, n0 = (bid & 511) << 1;

  // one-time prep for K2 (block 0): softplus'd params + Wl1 transpose (w1t[c][l])
  if (bid == 0) {
    if (t < 48) {
      const float* src = (t < 16) ? wsv : (t < 32 ? w1e : w2e);
      float v = src[t & 15];
      sp_ws[t] = fmaxf(v, 0.0f) + log1pf(expf(-fabsf(v)));
    }
    for (int idx = t; idx < 1024; idx += 256)
      w1t_ws[idx] = Wl1[(idx & 15) * 64 + (idx >> 4)];
  }

  const int ct0 = ct[b * NN];

  // exp_t for 2 positions
  if (t < 128) {
    const int p = t >> 6, g = t & 63;
    const int n = n0 + p;
    const bool same = (ct[b * NN + n] == ct0);
    const float tv = te[(size_t)(b * NN + n) * GG + g];
    const float xv = x[(size_t)(b * NN + n) * GG + g];
    const float sc = scal[g];
    s_exp[p * 64 + g] = (same ? tv : tv + xv) * (sc * sc);
  }
  __syncthreads();

  // data_ligand -> workspace
  if (t < 32) {
    const int p = t >> 4, l = t & 15;
    const int4 li = ((const int4*)lig)[l];
    const float gm0 = 0.5f * (s_exp[p * 64 + li.x] + s_exp[p * 64 + li.y]);
    const float gm1 = 0.5f * (s_exp[p * 64 + li.z] + s_exp[p * 64 + li.w]);
    dl_ws[((size_t)(b * NN + n0 + p) << 4) + l] = sqrtf(gm0 * gm1);
  }

  // GEMM1: thread t owns channels {t, t+256, t+512, t+768}, both positions
  float a00 = 0, a01 = 0, a02 = 0, a03 = 0, a10 = 0, a11 = 0, a12 = 0, a13 = 0;
  #pragma unroll 2
  for (int g = 0; g < 64; ++g) {
    const float w0 = W1[(size_t)g * H1 + t];
    const float w1 = W1[(size_t)g * H1 + t + 256];
    const float w2 = W1[(size_t)g * H1 + t + 512];
    const float w3 = W1[(size_t)g * H1 + t + 768];
    const float e0 = s_exp[g];          // broadcast
    const float e1 = s_exp[64 + g];
    a00 = fmaf(e0, w0, a00); a01 = fmaf(e0, w1, a01);
    a02 = fmaf(e0, w2, a02); a03 = fmaf(e0, w3, a03);
    a10 = fmaf(e1, w0, a10); a11 = fmaf(e1, w1, a11);
    a12 = fmaf(e1, w2, a12); a13 = fmaf(e1, w3, a13);
  }
  {
    const float bk0 = b1[t], bk1 = b1[t + 256], bk2 = b1[t + 512], bk3 = b1[t + 768];
    s_h[t * 3 + 0]          = gelu_f(a00 + bk0);
    s_h[t * 3 + 1]          = gelu_f(a10 + bk0);
    s_h[(t + 256) * 3 + 0]  = gelu_f(a01 + bk1);
    s_h[(t + 256) * 3 + 1]  = gelu_f(a11 + bk1);
    s_h[(t + 512) * 3 + 0]  = gelu_f(a02 + bk2);
    s_h[(t + 512) * 3 + 1]  = gelu_f(a12 + bk2);
    s_h[(t + 768) * 3 + 0]  = gelu_f(a03 + bk3);
    s_h[(t + 768) * 3 + 1]  = gelu_f(a13 + bk3);
  }
  __syncthreads();

  // GEMM2: wave w takes c-slice [w*256, w*256+256), lanes own 4 out-channels, both positions
  const int w = t >> 6, lane = t & 63, oc0 = lane << 2, cbase = w << 8;
  float z00 = 0, z01 = 0, z02 = 0, z03 = 0, z10 = 0, z11 = 0, z12 = 0, z13 = 0;
  #pragma unroll 4
  for (int c = cbase; c < cbase + 256; ++c) {
    const float4 wv = *(const float4*)&W2[(size_t)c * ND + oc0];
    const float h0 = s_h[c * 3 + 0];    // broadcast
    const float h1 = s_h[c * 3 + 1];
    z00 = fmaf(h0, wv.x, z00); z01 = fmaf(h0, wv.y, z01);
    z02 = fmaf(h0, wv.z, z02); z03 = fmaf(h0, wv.w, z03);
    z10 = fmaf(h1, wv.x, z10); z11 = fmaf(h1, wv.y, z11);
    z12 = fmaf(h1, wv.z, z12); z13 = fmaf(h1, wv.w, z13);
  }
  *(float4*)&s_part[((w << 1) + 0) * 256 + oc0] = make_float4(z00, z01, z02, z03);
  *(float4*)&s_part[((w << 1) + 1) * 256 + oc0] = make_float4(z10, z11, z12, z13);
  __syncthreads();

  // reduce partials + bias + ct_emb
  #pragma unroll
  for (int p = 0; p < 2; ++p) {
    const float v = s_part[(0 + p) * 256 + t] + s_part[(2 + p) * 256 + t] +
                    s_part[(4 + p) * 256 + t] + s_part[(6 + p) * 256 + t];
    const int cc = ct[b * NN + n0 + p];
    s_z[p * 256 + t] = v + b2[t] + ctemb[(size_t)cc * ND + t];
  }
  __syncthreads();

  // LayerNorm: wave 0 -> position 0, wave 1 -> position 1
  if (w < 2) {
    const float4 v4 = *(const float4*)&s_z[(w << 8) + (lane << 2)];
    float s = v4.x + v4.y + v4.z + v4.w;
    float sq = v4.x * v4.x + v4.y * v4.y + v4.z * v4.z + v4.w * v4.w;
    #pragma unroll
    for (int off = 1; off < 64; off <<= 1) {
      s += __shfl_xor(s, off);
      sq += __shfl_xor(sq, off);
    }
    const float m = s * (1.0f / 256.0f);
    const float var = sq * (1.0f / 256.0f) - m * m;
    const float rstd = rsqrtf(var + 1e-5f);
    const float4 g4 = *(const float4*)&lng[lane << 2];
    const float4 b4 = *(const float4*)&lnb[lane << 2];
    float4 o;
    o.x = (v4.x - m) * rstd * g4.x + b4.x;
    o.y = (v4.y - m) * rstd * g4.y + b4.y;
    o.z = (v4.z - m) * rstd * g4.z + b4.z;
    o.w = (v4.w - m) * rstd * g4.w + b4.w;
    *(float4*)&nf_out[((size_t)(b * NN + n0 + w) << 8) + (lane << 2)] = o;
  }
}

// ---------- K2: edges + emb1 + emb2 ----------
// 4 i-rows per thread as outer-2 x inner-2: only {dl, va, vb, oa, ob} live in the
// FFN loop (~100 VGPR vs ~160 for flat P=4) -> 4 resident waves/SIMD
// (__launch_bounds__(256,4) caps VGPR at 128). Weights via s_loads (SALU pipe).
__global__ __launch_bounds__(256, 4) void k_edges(
    const float* __restrict__ dist, const float* __restrict__ bsv,
    const float* __restrict__ b1e, const float* __restrict__ b2e,
    const float* __restrict__ w1t, const float* __restrict__ Wl2,
    const float* __restrict__ dl_ws, const float* __restrict__ sp,
    float* __restrict__ edges, float* __restrict__ em1, float* __restrict__ em2)
{
  const int t = threadIdx.x, bid = blockIdx.x;
  const int b = bid >> 10, r = bid & 1023;
  const int i0 = (r >> 2) << 2;          // 4 i-rows per block
  const int j = ((r & 3) << 8) + t;

  // per-j ligand vector (loop-invariant across i)
  float dl[16];
  {
    const float4* dp = (const float4*)&dl_ws[((size_t)(b * NN + j)) << 4];
    const float4 a0 = dp[0], a1 = dp[1], a2 = dp[2], a3 = dp[3];
    dl[0] = a0.x; dl[1] = a0.y; dl[2] = a0.z; dl[3] = a0.w;
    dl[4] = a1.x; dl[5] = a1.y; dl[6] = a1.z; dl[7] = a1.w;
    dl[8] = a2.x; dl[9] = a2.y; dl[10] = a2.z; dl[11] = a2.w;
    dl[12] = a3.x; dl[13] = a3.y; dl[14] = a3.z; dl[15] = a3.w;
  }

  #pragma unroll 1
  for (int pp = 0; pp < 2; ++pp) {
    const int ia = i0 + (pp << 1);
    const float da = dist[((size_t)(b * NN + ia) << 10) + j];
    const float db = dist[((size_t)(b * NN + ia + 1) << 10) + j];
    const size_t base_a = (((size_t)(b * NN + ia) << 10) + (size_t)j) << 4;
    const size_t base_b = base_a + ((size_t)NN << 4);   // +1 i-row = N*ED = 16384 floats

    // emb1/emb2 for both rows (temps die before the FFN)
    #pragma unroll
    for (int hr = 0; hr < 2; ++hr) {
      const float d = hr ? db : da;
      const size_t base = hr ? base_b : base_a;
      float q1[16], q2[16];
      #pragma unroll
      for (int e = 0; e < 16; ++e) {
        q1[e] = fsig(fmaf(d, sp[16 + e], b1e[e]));
        q2[e] = fmaf(d, sp[32 + e], b2e[e]) * 0.25f;
      }
      float4* e1p = (float4*)&em1[base];
      e1p[0] = make_float4(q1[0], q1[1], q1[2], q1[3]);
      e1p[1] = make_float4(q1[4], q1[5], q1[6], q1[7]);
      e1p[2] = make_float4(q1[8], q1[9], q1[10], q1[11]);
      e1p[3] = make_float4(q1[12], q1[13], q1[14], q1[15]);
      float4* e2p = (float4*)&em2[base];
      e2p[0] = make_float4(q2[0], q2[1], q2[2], q2[3]);
      e2p[1] = make_float4(q2[4], q2[5], q2[6], q2[7]);
      e2p[2] = make_float4(q2[8], q2[9], q2[10], q2[11]);
      e2p[3] = make_float4(q2[12], q2[13], q2[14], q2[15]);
    }

    // v = dl * sigmoid(d*softplus(ws)+bs), two rows
    float va[16], vb[16];
    #pragma unroll
    for (int l = 0; l < 16; ++l) {
      va[l] = dl[l] * fsig(fmaf(da, sp[l], bsv[l]));
      vb[l] = dl[l] * fsig(fmaf(db, sp[l], bsv[l]));
    }

    // FFN: o = gelu(v @ Wl1) @ Wl2, channel-by-channel, 2-row ILP + unroll-2
    float oa[16], ob[16];
    #pragma unroll
    for (int e = 0; e < 16; ++e) { oa[e] = 0.0f; ob[e] = 0.0f; }

    #pragma unroll 2
    for (int c = 0; c < 64; ++c) {
      const float* wc  = w1t + (c << 4);   // Wl1 column c (contiguous s_loads)
      const float* w2c = Wl2 + (c << 4);   // Wl2 row c
      float ha = va[0] * wc[0];
      float hb = vb[0] * wc[0];
      #pragma unroll
      for (int l = 1; l < 16; ++l) {
        ha = fmaf(va[l], wc[l], ha);
        hb = fmaf(vb[l], wc[l], hb);
      }
      const float ga = gelu_f(ha);
      const float gb = gelu_f(hb);
      #pragma unroll
      for (int e = 0; e < 16; ++e) {
        oa[e] = fmaf(ga, w2c[e], oa[e]);
        ob[e] = fmaf(gb, w2c[e], ob[e]);
      }
    }

    {
      float4* ep = (float4*)&edges[base_a];
      ep[0] = make_float4(oa[0], oa[1], oa[2], oa[3]);
      ep[1] = make_float4(oa[4], oa[5], oa[6], oa[7]);
      ep[2] = make_float4(oa[8], oa[9], oa[10], oa[11]);
      ep[3] = make_float4(oa[12], oa[13], oa[14], oa[15]);
      float4* fp = (float4*)&edges[base_b];
      fp[0] = make_float4(ob[0], ob[1], ob[2], ob[3]);
      fp[1] = make_float4(ob[4], ob[5], ob[6], ob[7]);
      fp[2] = make_float4(ob[8], ob[9], ob[10], ob[11]);
      fp[3] = make_float4(ob[12], ob[13], ob[14], ob[15]);
    }
  }
}

extern "C" void kernel_launch(void* const* d_in, const int* in_sizes, int n_in,
                              void* d_out, int out_size, void* d_ws, size_t ws_size,
                              hipStream_t stream)
{
  const float* x    = (const float*)d_in[0];
  const float* te   = (const float*)d_in[1];
  const float* dist = (const float*)d_in[2];
  const int*   ct   = (const int*)d_in[3];
  const float* scal = (const float*)d_in[4];
  const float* W1   = (const float*)d_in[5];
  const float* b1   = (const float*)d_in[6];
  const float* W2   = (const float*)d_in[7];
  const float* b2   = (const float*)d_in[8];
  const float* ctem = (const float*)d_in[9];
  const float* lng  = (const float*)d_in[10];
  const float* lnb  = (const float*)d_in[11];
  const float* wsv  = (const float*)d_in[12];
  const float* bsv  = (const float*)d_in[13];
  const float* w1e  = (const float*)d_in[14];
  const float* b1e  = (const float*)d_in[15];
  const float* w2e  = (const float*)d_in[16];
  const float* b2e  = (const float*)d_in[17];
  const float* Wl1  = (const float*)d_in[18];
  const float* Wl2  = (const float*)d_in[19];
  const int*   lig  = (const int*)d_in[20];

  float* out   = (float*)d_out;
  float* nf    = out;                    // (2,1024,256)
  float* edges = out + 524288;           // (2,1024,1024,16)
  float* em1   = out + 34078720;         // (2,1024,1024,16)
  float* em2   = out + 67633152;         // (2,1024,1024,16)

  float* dl_ws  = (float*)d_ws;                       // 32768 floats
  float* sp_ws  = dl_ws + (size_t)BB * NN * LL;       // 48 floats
  float* w1t_ws = sp_ws + 48;                         // 1024 floats (Wl1 transposed)

  hipLaunchKernelGGL(k_nf, dim3(1024), dim3(256), 0, stream,
      x, te, ct, scal, W1, b1, W2, b2, ctem, lng, lnb, lig, wsv, w1e, w2e, Wl1,
      dl_ws, sp_ws, w1t_ws, nf);

  hipLaunchKernelGGL(k_edges, dim3(2048), dim3(256), 0, stream,
      dist, bsv, b1e, b2e, w1t_ws, Wl2, dl_ws, sp_ws, edges, em1, em2);
}